// Round 1
// baseline (15313.930 us; speedup 1.0000x reference)
//
#include <hip/hip_runtime.h>
#include <hip/hip_cooperative_groups.h>
#include <math.h>

namespace cg = cooperative_groups;

#define NN    2048      // nodes == hidden
#define TT    64        // horizon
#define KIN   32768     // N_IN * N_NODES
#define KSTAT 30720     // static (non-recurrent) part of W_in columns
#define NBLK  256
#define TPB   512       // 8 waves/block -> 2048 waves total

__device__ __forceinline__ float wred(float v){
  #pragma unroll
  for (int m = 32; m > 0; m >>= 1) v += __shfl_xor(v, m, 64);
  return v;
}
__device__ __forceinline__ float sigm(float x){ return 1.0f / (1.0f + expf(-x)); }

__device__ __forceinline__ float dot2048(const float4* __restrict__ w4, const float4 v[8], int lane){
  float4 a = make_float4(0.f, 0.f, 0.f, 0.f);
  #pragma unroll
  for (int i = 0; i < 8; ++i){
    float4 w = w4[lane + (i << 6)];
    a.x = fmaf(w.x, v[i].x, a.x);
    a.y = fmaf(w.y, v[i].y, a.y);
    a.z = fmaf(w.z, v[i].z, a.z);
    a.w = fmaf(w.w, v[i].w, a.w);
  }
  return a.x + a.y + a.z + a.w;
}

// ---------- U[r][t] = b_in[r] + sum_{k<30720} W_in[r][k] * S[k][t]  (static input projection)
__global__ void k_pre(const float* __restrict__ Win, const float* __restrict__ bin,
                      const float* __restrict__ coords, const float* __restrict__ env,
                      const float* __restrict__ dusk, const float* __restrict__ dawn,
                      float* __restrict__ U)
{
  __shared__ float St[64][64];
  const int tid = threadIdx.x;
  const int col = tid & 63;          // t
  const int rg  = tid >> 6;          // wave id 0..3
  const int r0  = blockIdx.x * 8 + rg * 2;
  const int r1  = r0 + 1;
  float acc0 = 0.f, acc1 = 0.f;
  for (int kc = 0; kc < KSTAT; kc += 64){
    __syncthreads();
    #pragma unroll
    for (int jj = 0; jj < 16; ++jj){
      int idx = jj * 256 + tid;
      int kr = idx >> 6, tc = idx & 63;
      int k = kc + kr;
      float v;
      if (k < 4096)        v = coords[k];                         // coords_f (t-invariant)
      else if (k < 26624)  v = env[(k - 4096) * 65 + tc + 1];     // env[n][e][t+1], q=n*11+e
      else if (k < 28672)  v = dusk[(k - 26624) * 64 + tc];       // local_dusk[n][t]
      else                 v = dawn[(k - 28672) * 65 + tc + 1];   // local_dawn[n][t+1]
      St[kr][tc] = v;
    }
    __syncthreads();
    const float* w0 = Win + (size_t)r0 * KIN + kc;
    const float* w1 = Win + (size_t)r1 * KIN + kc;
    #pragma unroll
    for (int k = 0; k < 64; ++k){
      float s = St[k][col];
      acc0 = fmaf(w0[k], s, acc0);   // wave-uniform W address -> scalar loads
      acc1 = fmaf(w1[k], s, acc1);
    }
  }
  U[r0 * TT + col] = acc0 + bin[r0];
  U[r1 * TT + col] = acc1 + bin[r1];
}

// ---------- init states + output column 0
__global__ void k_init(const float* __restrict__ x, float* __restrict__ xs,
                       float* __restrict__ h0b, float* __restrict__ h1b,
                       float* __restrict__ c0, float* __restrict__ c1,
                       float* __restrict__ out)
{
  int i = blockIdx.x * blockDim.x + threadIdx.x;
  if (i < NN){
    float x0 = x[i * (TT + 1)];
    xs[i] = x0;
    out[i * (TT + 1)] = x0;
    h0b[i] = 0.f; h0b[NN + i] = 0.f;
    h1b[i] = 0.f; h1b[NN + i] = 0.f;
    c0[i] = 0.f;  c1[i] = 0.f;
  }
}

// ---------- one LSTM layer stage: one wave handles one hidden unit j (=wv): 4 gate rows x 2 dots
__device__ __forceinline__ void lstm_stage(const float* __restrict__ Wih, const float* __restrict__ Whh,
    const float* __restrict__ bih, const float* __restrict__ bhh,
    const float* __restrict__ vin_g, const float* __restrict__ hp_g,
    float* __restrict__ cst, float* __restrict__ hout, int wv, int lane)
{
  float4 vin[8], vh[8];
  #pragma unroll
  for (int i = 0; i < 8; ++i){
    vin[i] = ((const float4*)vin_g)[lane + (i << 6)];
    vh[i]  = ((const float4*)hp_g)[lane + (i << 6)];
  }
  float gs[4];
  #pragma unroll
  for (int g = 0; g < 4; ++g){
    const float4* wi4 = (const float4*)(Wih + (size_t)(g * NN + wv) * NN);
    const float4* wh4 = (const float4*)(Whh + (size_t)(g * NN + wv) * NN);
    float4 a = make_float4(0.f, 0.f, 0.f, 0.f);
    #pragma unroll
    for (int i = 0; i < 8; ++i){
      float4 w1 = wi4[lane + (i << 6)];
      float4 w2 = wh4[lane + (i << 6)];
      a.x = fmaf(w1.x, vin[i].x, fmaf(w2.x, vh[i].x, a.x));
      a.y = fmaf(w1.y, vin[i].y, fmaf(w2.y, vh[i].y, a.y));
      a.z = fmaf(w1.z, vin[i].z, fmaf(w2.z, vh[i].z, a.z));
      a.w = fmaf(w1.w, vin[i].w, fmaf(w2.w, vh[i].w, a.w));
    }
    gs[g] = wred(a.x + a.y + a.z + a.w);
  }
  if (lane == 0){
    float gi = sigm(gs[0] + bih[0 * NN + wv] + bhh[0 * NN + wv]);
    float gf = sigm(gs[1] + bih[1 * NN + wv] + bhh[1 * NN + wv]);
    float gg = tanhf(gs[2] + bih[2 * NN + wv] + bhh[2 * NN + wv]);
    float go = sigm(gs[3] + bih[3 * NN + wv] + bhh[3 * NN + wv]);
    float cn = fmaf(gf, cst[wv], gi * gg);
    cst[wv] = cn;
    hout[wv] = go * tanhf(cn);
  }
}

// ---------- persistent recurrent kernel: 2048 waves, 1 row per wave per stage, 4 grid syncs/step
__global__ __launch_bounds__(TPB) void k_main(
  const float* __restrict__ Win, const float* __restrict__ Wih, const float* __restrict__ Whh,
  const float* __restrict__ bih, const float* __restrict__ bhh,
  const float* __restrict__ Wout, const float* __restrict__ bout,
  const float* __restrict__ U, float* __restrict__ lin,
  float* __restrict__ h0b, float* __restrict__ h1b,
  float* __restrict__ c0, float* __restrict__ c1,
  float* __restrict__ xs, float* __restrict__ out)
{
  cg::grid_group grid = cg::this_grid();
  const int wv   = (int)blockIdx.x * (TPB / 64) + (int)(threadIdx.x >> 6);  // 0..2047
  const int lane = (int)threadIdx.x & 63;

  for (int t = 0; t < TT; ++t){
    const int p = t & 1;

    // ---- Stage A: lin = U[:,t] + W_in[:,30720:] @ x
    {
      float4 vx[8];
      #pragma unroll
      for (int i = 0; i < 8; ++i) vx[i] = ((const float4*)xs)[lane + (i << 6)];
      const float4* w4 = (const float4*)(Win + (size_t)wv * KIN + KSTAT);
      float s = wred(dot2048(w4, vx, lane));
      if (lane == 0) lin[wv] = U[wv * TT + t] + s;
    }
    grid.sync();

    // ---- Stage B: layer 0 gates + cell
    lstm_stage(Wih, Whh, bih, bhh,
               lin, h0b + p * NN, c0, h0b + (1 - p) * NN, wv, lane);
    grid.sync();

    // ---- Stage C: layer 1 gates + cell (input = new h0, hidden = prev h1)
    lstm_stage(Wih + (size_t)4 * NN * NN, Whh + (size_t)4 * NN * NN, bih + 4 * NN, bhh + 4 * NN,
               h0b + (1 - p) * NN, h1b + p * NN, c1, h1b + (1 - p) * NN, wv, lane);
    grid.sync();

    // ---- Stage D: x_new = x + tanh(W_out @ h1 + b_out); write output column t+1
    {
      const float* h1n = h1b + (1 - p) * NN;
      float4 vh[8];
      #pragma unroll
      for (int i = 0; i < 8; ++i) vh[i] = ((const float4*)h1n)[lane + (i << 6)];
      const float4* w4 = (const float4*)(Wout + (size_t)wv * NN);
      float s = wred(dot2048(w4, vh, lane));
      if (lane == 0){
        float xn = xs[wv] + tanhf(s + bout[wv]);
        xs[wv] = xn;
        out[wv * (TT + 1) + t + 1] = xn;
      }
    }
    grid.sync();
  }
}

extern "C" void kernel_launch(void* const* d_in, const int* in_sizes, int n_in,
                              void* d_out, int out_size, void* d_ws, size_t ws_size,
                              hipStream_t stream)
{
  const float* x      = (const float*)d_in[0];
  const float* coords = (const float*)d_in[1];
  const float* env    = (const float*)d_in[2];
  const float* dusk   = (const float*)d_in[3];
  const float* dawn   = (const float*)d_in[4];
  const float* Win    = (const float*)d_in[5];
  const float* bin    = (const float*)d_in[6];
  const float* Wih    = (const float*)d_in[7];
  const float* Whh    = (const float*)d_in[8];
  const float* bih    = (const float*)d_in[9];
  const float* bhh    = (const float*)d_in[10];
  const float* Wout   = (const float*)d_in[11];
  const float* bout   = (const float*)d_in[12];
  float* out = (float*)d_out;

  float* ws  = (float*)d_ws;
  float* U   = ws;               // 2048*64
  float* lin = U + NN * TT;      // 2048
  float* h0b = lin + NN;         // 2*2048 (double buffer)
  float* h1b = h0b + 2 * NN;     // 2*2048
  float* c0  = h1b + 2 * NN;     // 2048
  float* c1  = c0 + NN;          // 2048
  float* xs  = c1 + NN;          // 2048

  k_pre<<<dim3(NBLK), dim3(256), 0, stream>>>(Win, bin, coords, env, dusk, dawn, U);
  k_init<<<dim3(8), dim3(256), 0, stream>>>(x, xs, h0b, h1b, c0, c1, out);

  void* args[] = { (void*)&Win, (void*)&Wih, (void*)&Whh, (void*)&bih, (void*)&bhh,
                   (void*)&Wout, (void*)&bout, (void*)&U, (void*)&lin, (void*)&h0b,
                   (void*)&h1b, (void*)&c0, (void*)&c1, (void*)&xs, (void*)&out };
  hipLaunchCooperativeKernel((void*)k_main, dim3(NBLK), dim3(TPB), args, 0, stream);
}

// Round 2
// 4072.614 us; speedup vs baseline: 3.7602x; 3.7602x over previous
//
#include <hip/hip_runtime.h>
#include <math.h>

#define NN    2048      // nodes == hidden
#define TT    64        // horizon
#define KIN   32768     // N_IN * N_NODES
#define KSTAT 30720     // static (non-recurrent) part of W_in columns
#define KPART 8         // K-split for k_pre
#define KC    (KSTAT / KPART)   // 3840

__device__ __forceinline__ float wred(float v){
  #pragma unroll
  for (int m = 32; m > 0; m >>= 1) v += __shfl_xor(v, m, 64);
  return v;
}
__device__ __forceinline__ float sigm(float x){ return 1.0f / (1.0f + expf(-x)); }

// ---------- gather static input matrix S[k][t], k<30720, t<64 (coalesced writes)
__global__ void k_gather(const float* __restrict__ coords, const float* __restrict__ env,
                         const float* __restrict__ dusk, const float* __restrict__ dawn,
                         float* __restrict__ S)
{
  int idx = blockIdx.x * 256 + threadIdx.x;          // 30720*64 total, grid covers exactly
  int k = idx >> 6, t = idx & 63;
  float v;
  if (k < 4096)        v = coords[k];
  else if (k < 26624)  v = env[(size_t)(k - 4096) * 65 + t + 1];
  else if (k < 28672)  v = dusk[(size_t)(k - 26624) * 64 + t];
  else                 v = dawn[(size_t)(k - 28672) * 65 + t + 1];
  S[idx] = v;
}

// ---------- tiled GEMM: P[part][r][t] = sum_{k in part} W_in[r][k] * S[k][t]
// grid (128, 8), block 256. 16 rows x 64 cols per block, K-chunk 3840.
__global__ void k_pre(const float* __restrict__ Win, const float* __restrict__ S,
                      float* __restrict__ P)
{
  __shared__ float Wt[16 * 68];
  __shared__ float St[64 * 68];
  const int tid = threadIdx.x;
  const int rb  = blockIdx.x * 16;
  const int kp  = blockIdx.y;
  const int rc  = tid >> 4;              // 0..15
  const int t4  = (tid & 15) * 4;        // 0,4,...,60
  float4 acc = make_float4(0.f, 0.f, 0.f, 0.f);

  for (int kt = 0; kt < KC; kt += 64){
    const int kb = kp * KC + kt;
    __syncthreads();
    // W tile: row rc, k-offset t4 (coalesced float4 per row)
    *(float4*)(Wt + rc * 68 + t4) =
        *(const float4*)(Win + (size_t)(rb + rc) * KIN + kb + t4);
    // S tile: 64x64, 4 float4 per thread, coalesced
    #pragma unroll
    for (int jj = 0; jj < 4; ++jj){
      int li = jj * 1024 + tid * 4;
      int kr = li >> 6, tc = li & 63;
      *(float4*)(St + kr * 68 + tc) =
          *(const float4*)(S + (size_t)(kb + kr) * 64 + tc);
    }
    __syncthreads();
    #pragma unroll
    for (int k = 0; k < 64; ++k){
      float w = Wt[rc * 68 + k];
      float4 s = *(const float4*)(St + k * 68 + t4);
      acc.x = fmaf(w, s.x, acc.x);
      acc.y = fmaf(w, s.y, acc.y);
      acc.z = fmaf(w, s.z, acc.z);
      acc.w = fmaf(w, s.w, acc.w);
    }
  }
  *(float4*)(P + ((size_t)kp * NN + rb + rc) * TT + t4) = acc;
}

// ---------- U[r][t] = b_in[r] + sum_p P[p][r][t]
__global__ void k_reduce(const float* __restrict__ P, const float* __restrict__ bin,
                         float* __restrict__ U)
{
  int i = blockIdx.x * 256 + threadIdx.x;            // 131072 total
  float s = bin[i >> 6];
  #pragma unroll
  for (int p = 0; p < KPART; ++p) s += P[(size_t)p * NN * TT + i];
  U[i] = s;
}

// ---------- init states + output column 0
__global__ void k_init(const float* __restrict__ x, float* __restrict__ xs,
                       float* __restrict__ h0b, float* __restrict__ h1b,
                       float* __restrict__ c0, float* __restrict__ c1,
                       float* __restrict__ out)
{
  int i = blockIdx.x * blockDim.x + threadIdx.x;
  if (i < NN){
    float x0 = x[(size_t)i * (TT + 1)];
    xs[i] = x0;
    out[(size_t)i * (TT + 1)] = x0;
    h0b[i] = 0.f; h0b[NN + i] = 0.f;
    h1b[i] = 0.f; h1b[NN + i] = 0.f;
    c0[i] = 0.f;  c1[i] = 0.f;
  }
}

// ---------- stage A: lin[j] = U[j][t] + W_in[j, 30720:] @ xs   (one wave per row)
__global__ void k_lin(const float* __restrict__ Win, const float* __restrict__ U,
                      const float* __restrict__ xs, float* __restrict__ lin, int t)
{
  const int j    = blockIdx.x * 4 + (threadIdx.x >> 6);
  const int lane = threadIdx.x & 63;
  const float4* w4 = (const float4*)(Win + (size_t)j * KIN + KSTAT);
  const float4* x4 = (const float4*)xs;
  float4 a = make_float4(0.f, 0.f, 0.f, 0.f);
  #pragma unroll
  for (int i = 0; i < 8; ++i){
    float4 w = w4[lane + (i << 6)];
    float4 v = x4[lane + (i << 6)];
    a.x = fmaf(w.x, v.x, a.x); a.y = fmaf(w.y, v.y, a.y);
    a.z = fmaf(w.z, v.z, a.z); a.w = fmaf(w.w, v.w, a.w);
  }
  float s = wred(a.x + a.y + a.z + a.w);
  if (lane == 0) lin[j] = U[(size_t)j * TT + t] + s;
}

// ---------- one LSTM layer: block per hidden unit j, wave g per gate (i,f,g,o)
__global__ void k_lstm(const float* __restrict__ Wih_l, const float* __restrict__ Whh_l,
                       const float* __restrict__ bih_l, const float* __restrict__ bhh_l,
                       const float* __restrict__ vin, const float* __restrict__ hprev,
                       float* __restrict__ c, float* __restrict__ hout)
{
  __shared__ float gsm[4];
  const int j    = blockIdx.x;
  const int g    = threadIdx.x >> 6;
  const int lane = threadIdx.x & 63;
  const float4* wi4 = (const float4*)(Wih_l + (size_t)(g * NN + j) * NN);
  const float4* wh4 = (const float4*)(Whh_l + (size_t)(g * NN + j) * NN);
  const float4* vi4 = (const float4*)vin;
  const float4* hp4 = (const float4*)hprev;
  float4 a = make_float4(0.f, 0.f, 0.f, 0.f);
  #pragma unroll
  for (int i = 0; i < 8; ++i){
    float4 w1 = wi4[lane + (i << 6)];
    float4 v1 = vi4[lane + (i << 6)];
    float4 w2 = wh4[lane + (i << 6)];
    float4 v2 = hp4[lane + (i << 6)];
    a.x = fmaf(w1.x, v1.x, fmaf(w2.x, v2.x, a.x));
    a.y = fmaf(w1.y, v1.y, fmaf(w2.y, v2.y, a.y));
    a.z = fmaf(w1.z, v1.z, fmaf(w2.z, v2.z, a.z));
    a.w = fmaf(w1.w, v1.w, fmaf(w2.w, v2.w, a.w));
  }
  float s = wred(a.x + a.y + a.z + a.w);
  if (lane == 0) gsm[g] = s + bih_l[g * NN + j] + bhh_l[g * NN + j];
  __syncthreads();
  if (threadIdx.x == 0){
    float gi = sigm(gsm[0]);
    float gf = sigm(gsm[1]);
    float gg = tanhf(gsm[2]);
    float go = sigm(gsm[3]);
    float cn = fmaf(gf, c[j], gi * gg);
    c[j] = cn;
    hout[j] = go * tanhf(cn);
  }
}

// ---------- stage D: x += tanh(W_out @ h1 + b_out), write out[:, t+1]
__global__ void k_xout(const float* __restrict__ Wout, const float* __restrict__ bout,
                       const float* __restrict__ h1, float* __restrict__ xs,
                       float* __restrict__ out, int t)
{
  const int j    = blockIdx.x * 4 + (threadIdx.x >> 6);
  const int lane = threadIdx.x & 63;
  const float4* w4 = (const float4*)(Wout + (size_t)j * NN);
  const float4* h4 = (const float4*)h1;
  float4 a = make_float4(0.f, 0.f, 0.f, 0.f);
  #pragma unroll
  for (int i = 0; i < 8; ++i){
    float4 w = w4[lane + (i << 6)];
    float4 v = h4[lane + (i << 6)];
    a.x = fmaf(w.x, v.x, a.x); a.y = fmaf(w.y, v.y, a.y);
    a.z = fmaf(w.z, v.z, a.z); a.w = fmaf(w.w, v.w, a.w);
  }
  float s = wred(a.x + a.y + a.z + a.w);
  if (lane == 0){
    float xn = xs[j] + tanhf(s + bout[j]);
    xs[j] = xn;
    out[(size_t)j * (TT + 1) + t + 1] = xn;
  }
}

extern "C" void kernel_launch(void* const* d_in, const int* in_sizes, int n_in,
                              void* d_out, int out_size, void* d_ws, size_t ws_size,
                              hipStream_t stream)
{
  const float* x      = (const float*)d_in[0];
  const float* coords = (const float*)d_in[1];
  const float* env    = (const float*)d_in[2];
  const float* dusk   = (const float*)d_in[3];
  const float* dawn   = (const float*)d_in[4];
  const float* Win    = (const float*)d_in[5];
  const float* bin    = (const float*)d_in[6];
  const float* Wih    = (const float*)d_in[7];
  const float* Whh    = (const float*)d_in[8];
  const float* bih    = (const float*)d_in[9];
  const float* bhh    = (const float*)d_in[10];
  const float* Wout   = (const float*)d_in[11];
  const float* bout   = (const float*)d_in[12];
  float* out = (float*)d_out;

  float* ws  = (float*)d_ws;
  float* S   = ws;                       // 30720*64  = 1,966,080
  float* P   = S + (size_t)KSTAT * TT;   // 8*2048*64 = 1,048,576
  float* U   = P + (size_t)KPART * NN * TT; // 131,072
  float* lin = U + (size_t)NN * TT;      // 2048
  float* h0b = lin + NN;                 // 2*2048
  float* h1b = h0b + 2 * NN;             // 2*2048
  float* c0  = h1b + 2 * NN;             // 2048
  float* c1  = c0 + NN;                  // 2048
  float* xs  = c1 + NN;                  // 2048

  k_gather<<<dim3((KSTAT * TT) / 256), dim3(256), 0, stream>>>(coords, env, dusk, dawn, S);
  k_pre<<<dim3(128, KPART), dim3(256), 0, stream>>>(Win, S, P);
  k_reduce<<<dim3(NN * TT / 256), dim3(256), 0, stream>>>(P, bin, U);
  k_init<<<dim3(8), dim3(256), 0, stream>>>(x, xs, h0b, h1b, c0, c1, out);

  const size_t LOFF = (size_t)4 * NN * NN;   // layer offset in W_ih / W_hh
  for (int t = 0; t < TT; ++t){
    const int p = t & 1;
    k_lin<<<dim3(NN / 4), dim3(256), 0, stream>>>(Win, U, xs, lin, t);
    k_lstm<<<dim3(NN), dim3(256), 0, stream>>>(Wih, Whh, bih, bhh,
                                               lin, h0b + p * NN, c0, h0b + (1 - p) * NN);
    k_lstm<<<dim3(NN), dim3(256), 0, stream>>>(Wih + LOFF, Whh + LOFF, bih + 4 * NN, bhh + 4 * NN,
                                               h0b + (1 - p) * NN, h1b + p * NN, c1, h1b + (1 - p) * NN);
    k_xout<<<dim3(NN / 4), dim3(256), 0, stream>>>(Wout, bout, h1b + (1 - p) * NN, xs, out, t);
  }
}

// Round 3
// 2351.014 us; speedup vs baseline: 6.5138x; 1.7323x over previous
//
#include <hip/hip_runtime.h>
#include <math.h>

#define NN    2048      // nodes == hidden
#define TT    64        // horizon
#define KIN   32768     // N_IN * N_NODES
#define KSTAT 30720     // static (non-recurrent) part of W_in columns
#define KPART 8         // K-split for k_pre
#define KC    (KSTAT / KPART)   // 3840

typedef _Float16 half8v __attribute__((ext_vector_type(8)));

__device__ __forceinline__ float wred(float v){
  #pragma unroll
  for (int m = 32; m > 0; m >>= 1) v += __shfl_xor(v, m, 64);
  return v;
}
__device__ __forceinline__ float sigm(float x){ return 1.0f / (1.0f + expf(-x)); }

// 8-element weight/vector loads, f32 math regardless of storage type
__device__ __forceinline__ void load8(const _Float16* __restrict__ p, float* o){
  half8v h = *(const half8v*)p;
  #pragma unroll
  for (int i = 0; i < 8; ++i) o[i] = (float)h[i];
}
__device__ __forceinline__ void load8(const float* __restrict__ p, float* o){
  float4 a = *(const float4*)p, b = *(const float4*)(p + 4);
  o[0]=a.x; o[1]=a.y; o[2]=a.z; o[3]=a.w; o[4]=b.x; o[5]=b.y; o[6]=b.z; o[7]=b.w;
}

// ---------- f32 -> fp16 conversions (once per launch) ----------
__global__ void k_cvt(const float* __restrict__ s, _Float16* __restrict__ d){
  size_t i = ((size_t)blockIdx.x * 256 + threadIdx.x) * 8;
  float v[8]; load8(s + i, v);
  half8v h;
  #pragma unroll
  for (int q = 0; q < 8; ++q) h[q] = (_Float16)v[q];
  *(half8v*)(d + i) = h;
}
__global__ void k_cvt_tail(const float* __restrict__ Win, _Float16* __restrict__ dst){
  int r = blockIdx.x, c = threadIdx.x * 8;
  float v[8]; load8(Win + (size_t)r * KIN + KSTAT + c, v);
  half8v h;
  #pragma unroll
  for (int q = 0; q < 8; ++q) h[q] = (_Float16)v[q];
  *(half8v*)(dst + (size_t)r * NN + c) = h;
}

// ---------- gather static input matrix S[k][t] ----------
__global__ void k_gather(const float* __restrict__ coords, const float* __restrict__ env,
                         const float* __restrict__ dusk, const float* __restrict__ dawn,
                         float* __restrict__ S)
{
  int idx = blockIdx.x * 256 + threadIdx.x;
  int k = idx >> 6, t = idx & 63;
  float v;
  if (k < 4096)        v = coords[k];
  else if (k < 26624)  v = env[(size_t)(k - 4096) * 65 + t + 1];
  else if (k < 28672)  v = dusk[(size_t)(k - 26624) * 64 + t];
  else                 v = dawn[(size_t)(k - 28672) * 65 + t + 1];
  S[idx] = v;
}

// ---------- tiled GEMM: P[part][r][t] = sum_{k in part} W_in[r][k] * S[k][t] ----------
__global__ void k_pre(const float* __restrict__ Win, const float* __restrict__ S,
                      float* __restrict__ P)
{
  __shared__ float Wt[16 * 68];
  __shared__ float St[64 * 68];
  const int tid = threadIdx.x;
  const int rb  = blockIdx.x * 16;
  const int kp  = blockIdx.y;
  const int rc  = tid >> 4;
  const int t4  = (tid & 15) * 4;
  float4 acc = make_float4(0.f, 0.f, 0.f, 0.f);

  for (int kt = 0; kt < KC; kt += 64){
    const int kb = kp * KC + kt;
    __syncthreads();
    *(float4*)(Wt + rc * 68 + t4) =
        *(const float4*)(Win + (size_t)(rb + rc) * KIN + kb + t4);
    #pragma unroll
    for (int jj = 0; jj < 4; ++jj){
      int li = jj * 1024 + tid * 4;
      int kr = li >> 6, tc = li & 63;
      *(float4*)(St + kr * 68 + tc) =
          *(const float4*)(S + (size_t)(kb + kr) * 64 + tc);
    }
    __syncthreads();
    #pragma unroll
    for (int k = 0; k < 64; ++k){
      float w = Wt[rc * 68 + k];
      float4 s = *(const float4*)(St + k * 68 + t4);
      acc.x = fmaf(w, s.x, acc.x);
      acc.y = fmaf(w, s.y, acc.y);
      acc.z = fmaf(w, s.z, acc.z);
      acc.w = fmaf(w, s.w, acc.w);
    }
  }
  *(float4*)(P + ((size_t)kp * NN + rb + rc) * TT + t4) = acc;
}

// ---------- U[r][t] = b_in[r] + sum_p P[p][r][t] ----------
__global__ void k_reduce(const float* __restrict__ P, const float* __restrict__ bin,
                         float* __restrict__ U)
{
  int i = blockIdx.x * 256 + threadIdx.x;
  float s = bin[i >> 6];
  #pragma unroll
  for (int p = 0; p < KPART; ++p) s += P[(size_t)p * NN * TT + i];
  U[i] = s;
}

// ---------- init states + output column 0 ----------
__global__ void k_init(const float* __restrict__ x, float* __restrict__ xs,
                       float* __restrict__ h0b, float* __restrict__ h1b,
                       float* __restrict__ c0, float* __restrict__ c1,
                       float* __restrict__ out)
{
  int i = blockIdx.x * blockDim.x + threadIdx.x;
  if (i < NN){
    float x0 = x[(size_t)i * (TT + 1)];
    xs[i] = x0;
    out[(size_t)i * (TT + 1)] = x0;
    h0b[i] = 0.f; h0b[NN + i] = 0.f;
    h1b[i] = 0.f; h1b[NN + i] = 0.f;
    c0[i] = 0.f;  c1[i] = 0.f;
  }
}

// ---------- stage A: lin[j] = U[j][t] + Wtail[j,:] @ xs ----------
template<typename WT>
__global__ void k_lin_t(const WT* __restrict__ Wtail, size_t wstride,
                        const float* __restrict__ U, const float* __restrict__ xs,
                        float* __restrict__ lin, int t)
{
  const int j    = blockIdx.x * 4 + (threadIdx.x >> 6);
  const int lane = threadIdx.x & 63;
  const WT* w = Wtail + (size_t)j * wstride + lane * 8;
  const float* xv = xs + lane * 8;
  float acc = 0.f;
  #pragma unroll
  for (int ch = 0; ch < 4; ++ch){
    float wf[8], vf[8];
    load8(w + ch * 512, wf);
    load8(xv + ch * 512, vf);
    #pragma unroll
    for (int q = 0; q < 8; ++q) acc = fmaf(wf[q], vf[q], acc);
  }
  acc = wred(acc);
  if (lane == 0) lin[j] = U[(size_t)j * TT + t] + acc;
}

// ---------- one LSTM layer: block per hidden unit j, wave g per gate ----------
template<typename WT>
__global__ void k_lstm_t(const WT* __restrict__ Wih_l, const WT* __restrict__ Whh_l,
                         const float* __restrict__ bih_l, const float* __restrict__ bhh_l,
                         const float* __restrict__ vin, const float* __restrict__ hprev,
                         float* __restrict__ c, float* __restrict__ hout)
{
  __shared__ float gsm[4];
  const int j    = blockIdx.x;
  const int g    = threadIdx.x >> 6;
  const int lane = threadIdx.x & 63;
  const WT* wi = Wih_l + (size_t)(g * NN + j) * NN + lane * 8;
  const WT* wh = Whh_l + (size_t)(g * NN + j) * NN + lane * 8;
  const float* vi = vin + lane * 8;
  const float* hp = hprev + lane * 8;
  float acc = 0.f;
  #pragma unroll
  for (int ch = 0; ch < 4; ++ch){
    float w1[8], w2[8], v1[8], v2[8];
    load8(wi + ch * 512, w1); load8(vi + ch * 512, v1);
    load8(wh + ch * 512, w2); load8(hp + ch * 512, v2);
    #pragma unroll
    for (int q = 0; q < 8; ++q) acc = fmaf(w1[q], v1[q], fmaf(w2[q], v2[q], acc));
  }
  acc = wred(acc);
  if (lane == 0) gsm[g] = acc + bih_l[g * NN + j] + bhh_l[g * NN + j];
  __syncthreads();
  if (threadIdx.x == 0){
    float gi = sigm(gsm[0]);
    float gf = sigm(gsm[1]);
    float gg = tanhf(gsm[2]);
    float go = sigm(gsm[3]);
    float cn = fmaf(gf, c[j], gi * gg);
    c[j] = cn;
    hout[j] = go * tanhf(cn);
  }
}

// ---------- stage D: x += tanh(W_out @ h1 + b_out) ----------
template<typename WT>
__global__ void k_xout_t(const WT* __restrict__ Wout, const float* __restrict__ bout,
                         const float* __restrict__ h1, float* __restrict__ xs,
                         float* __restrict__ out, int t)
{
  const int j    = blockIdx.x * 4 + (threadIdx.x >> 6);
  const int lane = threadIdx.x & 63;
  const WT* w = Wout + (size_t)j * NN + lane * 8;
  const float* hv = h1 + lane * 8;
  float acc = 0.f;
  #pragma unroll
  for (int ch = 0; ch < 4; ++ch){
    float wf[8], vf[8];
    load8(w + ch * 512, wf);
    load8(hv + ch * 512, vf);
    #pragma unroll
    for (int q = 0; q < 8; ++q) acc = fmaf(wf[q], vf[q], acc);
  }
  acc = wred(acc);
  if (lane == 0){
    float xn = xs[j] + tanhf(acc + bout[j]);
    xs[j] = xn;
    out[(size_t)j * (TT + 1) + t + 1] = xn;
  }
}

extern "C" void kernel_launch(void* const* d_in, const int* in_sizes, int n_in,
                              void* d_out, int out_size, void* d_ws, size_t ws_size,
                              hipStream_t stream)
{
  const float* x      = (const float*)d_in[0];
  const float* coords = (const float*)d_in[1];
  const float* env    = (const float*)d_in[2];
  const float* dusk   = (const float*)d_in[3];
  const float* dawn   = (const float*)d_in[4];
  const float* Win    = (const float*)d_in[5];
  const float* bin    = (const float*)d_in[6];
  const float* Wih    = (const float*)d_in[7];
  const float* Whh    = (const float*)d_in[8];
  const float* bih    = (const float*)d_in[9];
  const float* bhh    = (const float*)d_in[10];
  const float* Wout   = (const float*)d_in[11];
  const float* bout   = (const float*)d_in[12];
  float* out = (float*)d_out;

  // ---- f32 scratch layout
  float* ws  = (float*)d_ws;
  float* S   = ws;                          // 30720*64
  float* P   = S + (size_t)KSTAT * TT;      // 8*2048*64
  float* U   = P + (size_t)KPART * NN * TT; // 131072
  float* lin = U + (size_t)NN * TT;
  float* h0b = lin + NN;
  float* h1b = h0b + 2 * NN;
  float* c0  = h1b + 2 * NN;
  float* c1  = c0 + NN;
  float* xs  = c1 + NN;
  float* f32_end = xs + NN;
  const size_t f32_bytes = (size_t)((char*)f32_end - (char*)d_ws);

  // ---- fp16 weight copies after the f32 block
  const size_t n_tail = (size_t)NN * NN;          //  4,194,304
  const size_t n_ih   = (size_t)2 * 4 * NN * NN;  // 33,554,432
  const size_t n_hh   = n_ih;
  const size_t n_out  = (size_t)NN * NN;
  const size_t fp16_bytes = (n_tail + n_ih + n_hh + n_out) * sizeof(_Float16);
  const bool use_fp16 = (ws_size >= f32_bytes + fp16_bytes);

  _Float16* Wt16  = (_Float16*)((char*)d_ws + f32_bytes);
  _Float16* Wih16 = Wt16 + n_tail;
  _Float16* Whh16 = Wih16 + n_ih;
  _Float16* Wo16  = Whh16 + n_hh;

  if (use_fp16){
    k_cvt_tail<<<dim3(NN), dim3(256), 0, stream>>>(Win, Wt16);
    k_cvt<<<dim3((int)(n_ih / 8 / 256)), dim3(256), 0, stream>>>(Wih, Wih16);
    k_cvt<<<dim3((int)(n_hh / 8 / 256)), dim3(256), 0, stream>>>(Whh, Whh16);
    k_cvt<<<dim3((int)(n_out / 8 / 256)), dim3(256), 0, stream>>>(Wout, Wo16);
  }

  k_gather<<<dim3((KSTAT * TT) / 256), dim3(256), 0, stream>>>(coords, env, dusk, dawn, S);
  k_pre<<<dim3(128, KPART), dim3(256), 0, stream>>>(Win, S, P);
  k_reduce<<<dim3(NN * TT / 256), dim3(256), 0, stream>>>(P, bin, U);
  k_init<<<dim3(8), dim3(256), 0, stream>>>(x, xs, h0b, h1b, c0, c1, out);

  const size_t LOFF = (size_t)4 * NN * NN;
  for (int t = 0; t < TT; ++t){
    const int p = t & 1;
    float* h0n = h0b + (1 - p) * NN;
    float* h0p = h0b + p * NN;
    float* h1n = h1b + (1 - p) * NN;
    float* h1p = h1b + p * NN;
    if (use_fp16){
      k_lin_t<_Float16><<<dim3(NN / 4), dim3(256), 0, stream>>>(Wt16, (size_t)NN, U, xs, lin, t);
      k_lstm_t<_Float16><<<dim3(NN), dim3(256), 0, stream>>>(Wih16, Whh16, bih, bhh,
                                                             lin, h0p, c0, h0n);
      k_lstm_t<_Float16><<<dim3(NN), dim3(256), 0, stream>>>(Wih16 + LOFF, Whh16 + LOFF,
                                                             bih + 4 * NN, bhh + 4 * NN,
                                                             h0n, h1p, c1, h1n);
      k_xout_t<_Float16><<<dim3(NN / 4), dim3(256), 0, stream>>>(Wo16, bout, h1n, xs, out, t);
    } else {
      k_lin_t<float><<<dim3(NN / 4), dim3(256), 0, stream>>>(Win + KSTAT, (size_t)KIN, U, xs, lin, t);
      k_lstm_t<float><<<dim3(NN), dim3(256), 0, stream>>>(Wih, Whh, bih, bhh,
                                                          lin, h0p, c0, h0n);
      k_lstm_t<float><<<dim3(NN), dim3(256), 0, stream>>>(Wih + LOFF, Whh + LOFF,
                                                          bih + 4 * NN, bhh + 4 * NN,
                                                          h0n, h1p, c1, h1n);
      k_xout_t<float><<<dim3(NN / 4), dim3(256), 0, stream>>>(Wout, bout, h1n, xs, out, t);
    }
  }
}

// Round 4
// 2070.647 us; speedup vs baseline: 7.3957x; 1.1354x over previous
//
#include <hip/hip_runtime.h>
#include <math.h>

#define NN    2048      // nodes == hidden
#define TT    64        // horizon
#define KIN   32768     // N_IN * N_NODES
#define KSTAT 30720     // static (non-recurrent) part of W_in columns
#define KPART 8         // K-split for k_pre
#define KC    (KSTAT / KPART)   // 3840

typedef _Float16 half8v __attribute__((ext_vector_type(8)));

__device__ __forceinline__ float wred(float v){
  #pragma unroll
  for (int m = 32; m > 0; m >>= 1) v += __shfl_xor(v, m, 64);
  return v;
}
__device__ __forceinline__ float sigm(float x){ return 1.0f / (1.0f + expf(-x)); }

__device__ __forceinline__ void load8(const _Float16* __restrict__ p, float* o){
  half8v h = *(const half8v*)p;
  #pragma unroll
  for (int i = 0; i < 8; ++i) o[i] = (float)h[i];
}
__device__ __forceinline__ void load8(const float* __restrict__ p, float* o){
  float4 a = *(const float4*)p, b = *(const float4*)(p + 4);
  o[0]=a.x; o[1]=a.y; o[2]=a.z; o[3]=a.w; o[4]=b.x; o[5]=b.y; o[6]=b.z; o[7]=b.w;
}

// ---------- f32 -> fp16 conversions ----------
__global__ void k_cvt(const float* __restrict__ s, _Float16* __restrict__ d){
  size_t i = ((size_t)blockIdx.x * 256 + threadIdx.x) * 8;
  float v[8]; load8(s + i, v);
  half8v h;
  #pragma unroll
  for (int q = 0; q < 8; ++q) h[q] = (_Float16)v[q];
  *(half8v*)(d + i) = h;
}
__global__ void k_cvt_tail(const float* __restrict__ Win, _Float16* __restrict__ dst){
  int r = blockIdx.x, c = threadIdx.x * 8;
  float v[8]; load8(Win + (size_t)r * KIN + KSTAT + c, v);
  half8v h;
  #pragma unroll
  for (int q = 0; q < 8; ++q) h[q] = (_Float16)v[q];
  *(half8v*)(dst + (size_t)r * NN + c) = h;
}

// ---------- f32 -> packed 12-bit (1-5-6 truncated fp16) ----------
// Lane owns weights {4*(lane+64c)+q : c=0..7,q=0..3}, field order k=4c+q.
// Row storage: 3 planes of 64 uint4 (fully coalesced read/write).
__global__ void k_pack(const float* __restrict__ W, uint4* __restrict__ P){
  const int row  = blockIdx.x * 4 + (threadIdx.x >> 6);
  const int lane = threadIdx.x & 63;
  const float4* W4 = (const float4*)(W + (size_t)row * NN);
  uint32_t u[12] = {0,0,0,0,0,0,0,0,0,0,0,0};
  #pragma unroll
  for (int c = 0; c < 8; ++c){
    float4 v = W4[lane + (c << 6)];
    float vv[4] = {v.x, v.y, v.z, v.w};
    #pragma unroll
    for (int q = 0; q < 4; ++q){
      _Float16 h = (_Float16)vv[q];
      unsigned short us = __builtin_bit_cast(unsigned short, h);
      us = (unsigned short)((us + 8) & 0xFFF0);          // round-to-nearest, keep 6 mantissa bits
      uint32_t f = (uint32_t)(us >> 4);
      int k = 4 * c + q, bp = 12 * k, w = bp >> 5, off = bp & 31;
      u[w] |= f << off;
      if (off > 20) u[w + 1] |= f >> (32 - off);
    }
  }
  uint4* p = P + (size_t)row * 192 + lane;
  p[0]   = make_uint4(u[0], u[1], u[2],  u[3]);
  p[64]  = make_uint4(u[4], u[5], u[6],  u[7]);
  p[128] = make_uint4(u[8], u[9], u[10], u[11]);
}

// ---------- packed-weight dot: one wave, one row of 2048 ----------
__device__ __forceinline__ float dot_packed(const uint4* __restrict__ base, int row,
                                            const float4* __restrict__ v4, int lane){
  const uint4* p = base + (size_t)row * 192 + lane;
  uint4 A = p[0], B = p[64], C = p[128];
  uint32_t u[12] = {A.x,A.y,A.z,A.w, B.x,B.y,B.z,B.w, C.x,C.y,C.z,C.w};
  float acc = 0.f;
  #pragma unroll
  for (int c = 0; c < 8; ++c){
    float4 v = v4[lane + (c << 6)];
    float vv[4] = {v.x, v.y, v.z, v.w};
    #pragma unroll
    for (int q = 0; q < 4; ++q){
      int k = 4 * c + q, bp = 12 * k, w = bp >> 5, off = bp & 31;
      uint32_t f = u[w] >> off;
      if (off > 20) f |= u[w + 1] << (32 - off);         // folds at compile time
      f &= 0xFFFu;
      float wt = (float)__builtin_bit_cast(_Float16, (unsigned short)(f << 4));
      acc = fmaf(wt, vv[q], acc);
    }
  }
  return acc;
}

// ---------- gather static input matrix S[k][t] ----------
__global__ void k_gather(const float* __restrict__ coords, const float* __restrict__ env,
                         const float* __restrict__ dusk, const float* __restrict__ dawn,
                         float* __restrict__ S)
{
  int idx = blockIdx.x * 256 + threadIdx.x;
  int k = idx >> 6, t = idx & 63;
  float v;
  if (k < 4096)        v = coords[k];
  else if (k < 26624)  v = env[(size_t)(k - 4096) * 65 + t + 1];
  else if (k < 28672)  v = dusk[(size_t)(k - 26624) * 64 + t];
  else                 v = dawn[(size_t)(k - 28672) * 65 + t + 1];
  S[idx] = v;
}

// ---------- tiled GEMM: P[part][r][t] = sum_{k in part} W_in[r][k] * S[k][t] ----------
__global__ void k_pre(const float* __restrict__ Win, const float* __restrict__ S,
                      float* __restrict__ P)
{
  __shared__ float Wt[16 * 68];
  __shared__ float St[64 * 68];
  const int tid = threadIdx.x;
  const int rb  = blockIdx.x * 16;
  const int kp  = blockIdx.y;
  const int rc  = tid >> 4;
  const int t4  = (tid & 15) * 4;
  float4 acc = make_float4(0.f, 0.f, 0.f, 0.f);

  for (int kt = 0; kt < KC; kt += 64){
    const int kb = kp * KC + kt;
    __syncthreads();
    *(float4*)(Wt + rc * 68 + t4) =
        *(const float4*)(Win + (size_t)(rb + rc) * KIN + kb + t4);
    #pragma unroll
    for (int jj = 0; jj < 4; ++jj){
      int li = jj * 1024 + tid * 4;
      int kr = li >> 6, tc = li & 63;
      *(float4*)(St + kr * 68 + tc) =
          *(const float4*)(S + (size_t)(kb + kr) * 64 + tc);
    }
    __syncthreads();
    #pragma unroll
    for (int k = 0; k < 64; ++k){
      float w = Wt[rc * 68 + k];
      float4 s = *(const float4*)(St + k * 68 + t4);
      acc.x = fmaf(w, s.x, acc.x);
      acc.y = fmaf(w, s.y, acc.y);
      acc.z = fmaf(w, s.z, acc.z);
      acc.w = fmaf(w, s.w, acc.w);
    }
  }
  *(float4*)(P + ((size_t)kp * NN + rb + rc) * TT + t4) = acc;
}

// ---------- U[r][t] = b_in[r] + sum_p P[p][r][t] ----------
__global__ void k_reduce(const float* __restrict__ P, const float* __restrict__ bin,
                         float* __restrict__ U)
{
  int i = blockIdx.x * 256 + threadIdx.x;
  float s = bin[i >> 6];
  #pragma unroll
  for (int p = 0; p < KPART; ++p) s += P[(size_t)p * NN * TT + i];
  U[i] = s;
}

// ---------- init states + output column 0 ----------
__global__ void k_init(const float* __restrict__ x, float* __restrict__ xs,
                       float* __restrict__ h0b, float* __restrict__ h1b,
                       float* __restrict__ c0, float* __restrict__ c1,
                       float* __restrict__ out)
{
  int i = blockIdx.x * blockDim.x + threadIdx.x;
  if (i < NN){
    float x0 = x[(size_t)i * (TT + 1)];
    xs[i] = x0;
    out[(size_t)i * (TT + 1)] = x0;
    h0b[i] = 0.f; h0b[NN + i] = 0.f;
    h1b[i] = 0.f; h1b[NN + i] = 0.f;
    c0[i] = 0.f;  c1[i] = 0.f;
  }
}

// ---------- stage A: lin[j] = U[j][t] + Wtail[j,:] @ xs ----------
template<typename WT>
__global__ void k_lin_t(const WT* __restrict__ Wtail, size_t wstride,
                        const float* __restrict__ U, const float* __restrict__ xs,
                        float* __restrict__ lin, int t)
{
  const int j    = blockIdx.x * 4 + (threadIdx.x >> 6);
  const int lane = threadIdx.x & 63;
  const WT* w = Wtail + (size_t)j * wstride + lane * 8;
  const float* xv = xs + lane * 8;
  float acc = 0.f;
  #pragma unroll
  for (int ch = 0; ch < 4; ++ch){
    float wf[8], vf[8];
    load8(w + ch * 512, wf);
    load8(xv + ch * 512, vf);
    #pragma unroll
    for (int q = 0; q < 8; ++q) acc = fmaf(wf[q], vf[q], acc);
  }
  acc = wred(acc);
  if (lane == 0) lin[j] = U[(size_t)j * TT + t] + acc;
}

// ---------- LSTM layer, packed 12-bit weights: block per unit j, wave per gate ----------
__global__ void k_lstm_p(const uint4* __restrict__ Pih, const uint4* __restrict__ Phh,
                         const float* __restrict__ bih_l, const float* __restrict__ bhh_l,
                         const float* __restrict__ vin, const float* __restrict__ hprev,
                         float* __restrict__ c, float* __restrict__ hout)
{
  __shared__ float gsm[4];
  const int j    = blockIdx.x;
  const int g    = threadIdx.x >> 6;
  const int lane = threadIdx.x & 63;
  const int row  = g * NN + j;
  float acc = dot_packed(Pih, row, (const float4*)vin,  lane)
            + dot_packed(Phh, row, (const float4*)hprev, lane);
  acc = wred(acc);
  if (lane == 0) gsm[g] = acc + bih_l[g * NN + j] + bhh_l[g * NN + j];
  __syncthreads();
  if (threadIdx.x == 0){
    float gi = sigm(gsm[0]);
    float gf = sigm(gsm[1]);
    float gg = tanhf(gsm[2]);
    float go = sigm(gsm[3]);
    float cn = fmaf(gf, c[j], gi * gg);
    c[j] = cn;
    hout[j] = go * tanhf(cn);
  }
}

// ---------- LSTM layer, f32 fallback ----------
template<typename WT>
__global__ void k_lstm_t(const WT* __restrict__ Wih_l, const WT* __restrict__ Whh_l,
                         const float* __restrict__ bih_l, const float* __restrict__ bhh_l,
                         const float* __restrict__ vin, const float* __restrict__ hprev,
                         float* __restrict__ c, float* __restrict__ hout)
{
  __shared__ float gsm[4];
  const int j    = blockIdx.x;
  const int g    = threadIdx.x >> 6;
  const int lane = threadIdx.x & 63;
  const WT* wi = Wih_l + (size_t)(g * NN + j) * NN + lane * 8;
  const WT* wh = Whh_l + (size_t)(g * NN + j) * NN + lane * 8;
  const float* vi = vin + lane * 8;
  const float* hp = hprev + lane * 8;
  float acc = 0.f;
  #pragma unroll
  for (int ch = 0; ch < 4; ++ch){
    float w1[8], w2[8], v1[8], v2[8];
    load8(wi + ch * 512, w1); load8(vi + ch * 512, v1);
    load8(wh + ch * 512, w2); load8(hp + ch * 512, v2);
    #pragma unroll
    for (int q = 0; q < 8; ++q) acc = fmaf(w1[q], v1[q], fmaf(w2[q], v2[q], acc));
  }
  acc = wred(acc);
  if (lane == 0) gsm[g] = acc + bih_l[g * NN + j] + bhh_l[g * NN + j];
  __syncthreads();
  if (threadIdx.x == 0){
    float gi = sigm(gsm[0]);
    float gf = sigm(gsm[1]);
    float gg = tanhf(gsm[2]);
    float go = sigm(gsm[3]);
    float cn = fmaf(gf, c[j], gi * gg);
    c[j] = cn;
    hout[j] = go * tanhf(cn);
  }
}

// ---------- stage D: x += tanh(W_out @ h1 + b_out) ----------
template<typename WT>
__global__ void k_xout_t(const WT* __restrict__ Wout, const float* __restrict__ bout,
                         const float* __restrict__ h1, float* __restrict__ xs,
                         float* __restrict__ out, int t)
{
  const int j    = blockIdx.x * 4 + (threadIdx.x >> 6);
  const int lane = threadIdx.x & 63;
  const WT* w = Wout + (size_t)j * NN + lane * 8;
  const float* hv = h1 + lane * 8;
  float acc = 0.f;
  #pragma unroll
  for (int ch = 0; ch < 4; ++ch){
    float wf[8], vf[8];
    load8(w + ch * 512, wf);
    load8(hv + ch * 512, vf);
    #pragma unroll
    for (int q = 0; q < 8; ++q) acc = fmaf(wf[q], vf[q], acc);
  }
  acc = wred(acc);
  if (lane == 0){
    float xn = xs[j] + tanhf(acc + bout[j]);
    xs[j] = xn;
    out[(size_t)j * (TT + 1) + t + 1] = xn;
  }
}

extern "C" void kernel_launch(void* const* d_in, const int* in_sizes, int n_in,
                              void* d_out, int out_size, void* d_ws, size_t ws_size,
                              hipStream_t stream)
{
  const float* x      = (const float*)d_in[0];
  const float* coords = (const float*)d_in[1];
  const float* env    = (const float*)d_in[2];
  const float* dusk   = (const float*)d_in[3];
  const float* dawn   = (const float*)d_in[4];
  const float* Win    = (const float*)d_in[5];
  const float* bin    = (const float*)d_in[6];
  const float* Wih    = (const float*)d_in[7];
  const float* Whh    = (const float*)d_in[8];
  const float* bih    = (const float*)d_in[9];
  const float* bhh    = (const float*)d_in[10];
  const float* Wout   = (const float*)d_in[11];
  const float* bout   = (const float*)d_in[12];
  float* out = (float*)d_out;

  // ---- f32 scratch layout
  float* ws  = (float*)d_ws;
  float* S   = ws;                          // 30720*64
  float* P   = S + (size_t)KSTAT * TT;      // 8*2048*64
  float* U   = P + (size_t)KPART * NN * TT; // 131072
  float* lin = U + (size_t)NN * TT;
  float* h0b = lin + NN;
  float* h1b = h0b + 2 * NN;
  float* c0  = h1b + 2 * NN;
  float* c1  = c0 + NN;
  float* xs  = c1 + NN;
  float* f32_end = xs + NN;
  const size_t f32_bytes = (size_t)((char*)f32_end - (char*)d_ws);

  // ---- packed 12-bit W_ih/W_hh (both layers) + fp16 W_tail/W_out
  const size_t rows_per_w   = (size_t)2 * 4 * NN;          // 16384 rows each
  const size_t packed_bytes = rows_per_w * 64 * 48;        // 3072 B/row = 50.33 MB
  const size_t n_tail = (size_t)NN * NN;
  const size_t n_out  = (size_t)NN * NN;

  uint4*     PIH  = (uint4*)((char*)d_ws + f32_bytes);
  uint4*     PHH  = (uint4*)((char*)PIH + packed_bytes);
  _Float16*  Wt16 = (_Float16*)((char*)PHH + packed_bytes);
  _Float16*  Wo16 = Wt16 + n_tail;
  const size_t needed = f32_bytes + 2 * packed_bytes + (n_tail + n_out) * sizeof(_Float16);
  const bool use_q = (ws_size >= needed);

  if (use_q){
    k_pack<<<dim3((int)(rows_per_w / 4)), dim3(256), 0, stream>>>(Wih, PIH);
    k_pack<<<dim3((int)(rows_per_w / 4)), dim3(256), 0, stream>>>(Whh, PHH);
    k_cvt_tail<<<dim3(NN), dim3(256), 0, stream>>>(Win, Wt16);
    k_cvt<<<dim3((int)(n_out / 8 / 256)), dim3(256), 0, stream>>>(Wout, Wo16);
  }

  k_gather<<<dim3((KSTAT * TT) / 256), dim3(256), 0, stream>>>(coords, env, dusk, dawn, S);
  k_pre<<<dim3(128, KPART), dim3(256), 0, stream>>>(Win, S, P);
  k_reduce<<<dim3(NN * TT / 256), dim3(256), 0, stream>>>(P, bin, U);
  k_init<<<dim3(8), dim3(256), 0, stream>>>(x, xs, h0b, h1b, c0, c1, out);

  const size_t LOFF   = (size_t)4 * NN * NN;       // layer offset, f32 elements
  const size_t LROWS  = (size_t)4 * NN * 192;      // layer offset, uint4 units (8192 rows * 192)
  for (int t = 0; t < TT; ++t){
    const int p = t & 1;
    float* h0n = h0b + (1 - p) * NN;
    float* h0p = h0b + p * NN;
    float* h1n = h1b + (1 - p) * NN;
    float* h1p = h1b + p * NN;
    if (use_q){
      k_lin_t<_Float16><<<dim3(NN / 4), dim3(256), 0, stream>>>(Wt16, (size_t)NN, U, xs, lin, t);
      k_lstm_p<<<dim3(NN), dim3(256), 0, stream>>>(PIH, PHH, bih, bhh, lin, h0p, c0, h0n);
      k_lstm_p<<<dim3(NN), dim3(256), 0, stream>>>(PIH + LROWS, PHH + LROWS,
                                                   bih + 4 * NN, bhh + 4 * NN,
                                                   h0n, h1p, c1, h1n);
      k_xout_t<_Float16><<<dim3(NN / 4), dim3(256), 0, stream>>>(Wo16, bout, h1n, xs, out, t);
    } else {
      k_lin_t<float><<<dim3(NN / 4), dim3(256), 0, stream>>>(Win + KSTAT, (size_t)KIN, U, xs, lin, t);
      k_lstm_t<float><<<dim3(NN), dim3(256), 0, stream>>>(Wih, Whh, bih, bhh,
                                                          lin, h0p, c0, h0n);
      k_lstm_t<float><<<dim3(NN), dim3(256), 0, stream>>>(Wih + LOFF, Whh + LOFF,
                                                          bih + 4 * NN, bhh + 4 * NN,
                                                          h0n, h1p, c1, h1n);
      k_xout_t<float><<<dim3(NN / 4), dim3(256), 0, stream>>>(Wout, bout, h1n, xs, out, t);
    }
  }
}